// Round 4
// baseline (908.763 us; speedup 1.0000x reference)
//
#include <hip/hip_runtime.h>
#include <hip/hip_bf16.h>

typedef __attribute__((ext_vector_type(8))) short bf16x8;
typedef __attribute__((ext_vector_type(4))) float f32x4;

constexpr int BATCH = 32, SEQ = 3136, DIM = 768, NH = 12, HD = 64;
constexpr int M_TOT = BATCH * SEQ;   // 100352
constexpr int QKVC  = 3 * DIM;       // 2304
constexpr int GK    = 768;           // K for both GEMMs

__device__ __forceinline__ float bf2f(unsigned short u) {
  union { unsigned int i; float f; } x; x.i = ((unsigned int)u) << 16; return x.f;
}
__device__ __forceinline__ unsigned short f2bf(float f) {
  union { float f; unsigned int i; } x; x.f = f;
  unsigned int r = x.i + 0x7FFFu + ((x.i >> 16) & 1u);
  return (unsigned short)(r >> 16);
}
__device__ __forceinline__ unsigned int pack2(float lo, float hi) {
  return (unsigned int)f2bf(lo) | ((unsigned int)f2bf(hi) << 16);
}
__device__ __forceinline__ void gload_lds16(const unsigned short* g, unsigned short* l) {
  __builtin_amdgcn_global_load_lds(
      (const __attribute__((address_space(1))) void*)g,
      (__attribute__((address_space(3))) void*)l, 16, 0, 0);
}

#define BARX()  asm volatile("s_barrier" ::: "memory")
#define LGKM0() asm volatile("s_waitcnt lgkmcnt(0)" ::: "memory")
#define VM8()   asm volatile("s_waitcnt vmcnt(8)" ::: "memory")
#define VM4()   asm volatile("s_waitcnt vmcnt(4)" ::: "memory")
#define SB0()   __builtin_amdgcn_sched_barrier(0)

// ---------------- fp32 -> bf16 elementwise ----------------
__global__ void conv_kernel(const float* __restrict__ in, unsigned short* __restrict__ out, long n) {
  long i = ((long)blockIdx.x * blockDim.x + threadIdx.x) * 8;
  long stride = (long)gridDim.x * blockDim.x * 8;
  for (; i < n; i += stride) {
    float4 a = *(const float4*)(in + i);
    float4 b = *(const float4*)(in + i + 4);
    uint4 o;
    o.x = pack2(a.x, a.y); o.y = pack2(a.z, a.w);
    o.z = pack2(b.x, b.y); o.w = pack2(b.z, b.w);
    *(uint4*)(out + i) = o;
  }
}

// ---------------- transpose+convert: w[K][N] fp32 -> wt[N][K] bf16 ----------------
__global__ void transp_kernel(const float* __restrict__ w, unsigned short* __restrict__ wt, int K, int N) {
  __shared__ float tile[32][33];
  int n0 = blockIdx.x * 32, k0 = blockIdx.y * 32;
  int tx = threadIdx.x, ty = threadIdx.y;
  #pragma unroll
  for (int i = 0; i < 32; i += 8)
    tile[ty + i][tx] = w[(size_t)(k0 + ty + i) * N + n0 + tx];
  __syncthreads();
  #pragma unroll
  for (int i = 0; i < 32; i += 8)
    wt[(size_t)(n0 + ty + i) * K + k0 + tx] = f2bf(tile[tx][ty + i]);
}

// ---------------- persistent 256x256x64 GEMM, reg-double-buffered frag prefetch ----------------
__device__ __forceinline__ void stage_half(const unsigned short* __restrict__ G, long row0, int col0,
                                           unsigned short* ldsHalf, int t) {
  int r = t >> 2;
  int gslot = (t & 3) ^ ((t >> 3) & 3);
  char* dst = (char*)ldsHalf + ((t >> 6) << 10);  // wave-uniform base; HW adds lane*16
  gload_lds16(G + (row0 + r) * (long)GK + col0 + gslot * 8, (unsigned short*)dst);
  gload_lds16(G + (row0 + 128 + r) * (long)GK + col0 + gslot * 8, (unsigned short*)(dst + 8192));
}
__device__ __forceinline__ bf16x8 frag(const unsigned short* half, int r, int ko) {
  return *(const bf16x8*)((const char*)half + r * 64 + ((((ko >> 3) ^ ((r >> 1) & 3))) << 4));
}

#define MM16G(Q,A0,A1,A2,A3,B0,B1,B2,B3) do { \
  acc[(Q)+0][0]=__builtin_amdgcn_mfma_f32_16x16x32_bf16(A0,B0,acc[(Q)+0][0],0,0,0); \
  acc[(Q)+0][1]=__builtin_amdgcn_mfma_f32_16x16x32_bf16(A0,B1,acc[(Q)+0][1],0,0,0); \
  acc[(Q)+0][2]=__builtin_amdgcn_mfma_f32_16x16x32_bf16(A0,B2,acc[(Q)+0][2],0,0,0); \
  acc[(Q)+0][3]=__builtin_amdgcn_mfma_f32_16x16x32_bf16(A0,B3,acc[(Q)+0][3],0,0,0); \
  acc[(Q)+1][0]=__builtin_amdgcn_mfma_f32_16x16x32_bf16(A1,B0,acc[(Q)+1][0],0,0,0); \
  acc[(Q)+1][1]=__builtin_amdgcn_mfma_f32_16x16x32_bf16(A1,B1,acc[(Q)+1][1],0,0,0); \
  acc[(Q)+1][2]=__builtin_amdgcn_mfma_f32_16x16x32_bf16(A1,B2,acc[(Q)+1][2],0,0,0); \
  acc[(Q)+1][3]=__builtin_amdgcn_mfma_f32_16x16x32_bf16(A1,B3,acc[(Q)+1][3],0,0,0); \
  acc[(Q)+2][0]=__builtin_amdgcn_mfma_f32_16x16x32_bf16(A2,B0,acc[(Q)+2][0],0,0,0); \
  acc[(Q)+2][1]=__builtin_amdgcn_mfma_f32_16x16x32_bf16(A2,B1,acc[(Q)+2][1],0,0,0); \
  acc[(Q)+2][2]=__builtin_amdgcn_mfma_f32_16x16x32_bf16(A2,B2,acc[(Q)+2][2],0,0,0); \
  acc[(Q)+2][3]=__builtin_amdgcn_mfma_f32_16x16x32_bf16(A2,B3,acc[(Q)+2][3],0,0,0); \
  acc[(Q)+3][0]=__builtin_amdgcn_mfma_f32_16x16x32_bf16(A3,B0,acc[(Q)+3][0],0,0,0); \
  acc[(Q)+3][1]=__builtin_amdgcn_mfma_f32_16x16x32_bf16(A3,B1,acc[(Q)+3][1],0,0,0); \
  acc[(Q)+3][2]=__builtin_amdgcn_mfma_f32_16x16x32_bf16(A3,B2,acc[(Q)+3][2],0,0,0); \
  acc[(Q)+3][3]=__builtin_amdgcn_mfma_f32_16x16x32_bf16(A3,B3,acc[(Q)+3][3],0,0,0); \
} while (0)

// K-tile with frag-register double buffering. Each phase: lgkm0 (prev prefetch already
// drained), [VM4 at P1/P3], prefetch next phase's frags, issue stage, MFMA cluster, BARX.
// ONE barrier per phase; LDS drain overlaps MFMA. vmcnt(4) ledger: P1 confirms ks1(J)
// (S1,S2 of J-1) before P2's prefetch; P3 confirms ks0(J+1) before P4's prefetch. All
// confirmations are VM4 + BARX before the dependent read issue (all-waves-safe).
#define KTILE_P(BUF, MA2, NB2, C2, MA3, NB3, C3) { \
  const unsigned short* Ah0 = &lds[BUF][0][0][0]; \
  const unsigned short* Bh0 = &lds[BUF][1][0][0]; \
  const unsigned short* Ah1 = &lds[BUF][0][1][0]; \
  const unsigned short* Bh1 = &lds[BUF][1][1][0]; \
  const unsigned short* Ah0n = &lds[(BUF) ^ 1][0][0][0]; \
  const unsigned short* Bh0n = &lds[(BUF) ^ 1][1][0][0]; \
  /* P1: MFMA(a0-3 x b0-3) ks0/mq0 ; prefetch a4-7 <- ks0 mq1 ; stage S1 ; VM4 */ \
  LGKM0(); SB0(); VM4(); \
  a4 = frag(Ah0, ra + 64, ko); a5 = frag(Ah0, ra + 80, ko); \
  a6 = frag(Ah0, ra + 96, ko); a7 = frag(Ah0, ra + 112, ko); \
  stage_half(A, MA2, C2, &lds[(BUF) ^ 1][0][1][0], t); \
  __builtin_amdgcn_s_setprio(1); MM16G(0, a0, a1, a2, a3, b0, b1, b2, b3); \
  __builtin_amdgcn_s_setprio(0); SB0(); BARX(); \
  /* P2: MFMA(a4-7 x b0-3) ks0/mq1 ; prefetch a0-3 <- ks1 mq0, b4-7 <- ks1 ; stage S2 */ \
  LGKM0(); SB0(); \
  a0 = frag(Ah1, ra,      ko); a1 = frag(Ah1, ra + 16, ko); \
  a2 = frag(Ah1, ra + 32, ko); a3 = frag(Ah1, ra + 48, ko); \
  b4 = frag(Bh1, rb,      ko); b5 = frag(Bh1, rb + 16, ko); \
  b6 = frag(Bh1, rb + 32, ko); b7 = frag(Bh1, rb + 48, ko); \
  stage_half(Bt, NB2, C2, &lds[(BUF) ^ 1][1][1][0], t); \
  __builtin_amdgcn_s_setprio(1); MM16G(4, a4, a5, a6, a7, b0, b1, b2, b3); \
  __builtin_amdgcn_s_setprio(0); SB0(); BARX(); \
  /* P3: MFMA(a0-3 x b4-7) ks1/mq0 ; prefetch a4-7 <- ks1 mq1 ; stage S3 ; VM4 */ \
  LGKM0(); SB0(); VM4(); \
  a4 = frag(Ah1, ra + 64, ko); a5 = frag(Ah1, ra + 80, ko); \
  a6 = frag(Ah1, ra + 96, ko); a7 = frag(Ah1, ra + 112, ko); \
  stage_half(A, MA3, C3, &lds[BUF][0][0][0], t); \
  __builtin_amdgcn_s_setprio(1); MM16G(0, a0, a1, a2, a3, b4, b5, b6, b7); \
  __builtin_amdgcn_s_setprio(0); SB0(); BARX(); \
  /* P4: MFMA(a4-7 x b4-7) ks1/mq1 ; prefetch a0-3,b0-3 <- next K-tile ks0 ; stage S4 */ \
  LGKM0(); SB0(); \
  a0 = frag(Ah0n, ra,      ko); a1 = frag(Ah0n, ra + 16, ko); \
  a2 = frag(Ah0n, ra + 32, ko); a3 = frag(Ah0n, ra + 48, ko); \
  b0 = frag(Bh0n, rb,      ko); b1 = frag(Bh0n, rb + 16, ko); \
  b2 = frag(Bh0n, rb + 32, ko); b3 = frag(Bh0n, rb + 48, ko); \
  stage_half(Bt, NB3, C3, &lds[BUF][1][0][0], t); \
  __builtin_amdgcn_s_setprio(1); MM16G(4, a4, a5, a6, a7, b4, b5, b6, b7); \
  __builtin_amdgcn_s_setprio(0); SB0(); BARX(); \
}

template<int OUTMODE, int NT>
__global__ __launch_bounds__(512, 2) void gemm256p(const unsigned short* __restrict__ A,
                                                   const unsigned short* __restrict__ Bt,
                                                   void* __restrict__ Cp,
                                                   const float* __restrict__ bias,
                                                   int Nld, int TPX) {
  __shared__ unsigned short lds[2][2][2][8192];  // [buf][A/B][ks][256*32], 128 KiB
  int t = threadIdx.x, lane = t & 63, wid = t >> 6;
  int wm = wid >> 2, wn = wid & 3;
  int bid = (int)blockIdx.x;
  int xcd = bid & 7, slot = bid >> 3;
  int tau = xcd * TPX + slot;
  int tend = (xcd + 1) * TPX;
  int fl = lane & 15, ko = (lane >> 4) * 8;
  int ra = wm * 128 + fl, rb = wn * 64 + fl;
  f32x4 acc[8][4];
  bf16x8 a0, a1, a2, a3, a4, a5, a6, a7, b0, b1, b2, b3, b4, b5, b6, b7;
  // prologue: stage tile0 buf0(ks0,ks1) + buf1(ks0); VM8 confirms ks0(0); prime frags
  {
    long m0 = (long)(tau / NT) * 256, n0 = (long)(tau % NT) * 256;
    stage_half(A,  m0, 0,  &lds[0][0][0][0], t);
    stage_half(Bt, n0, 0,  &lds[0][1][0][0], t);
    stage_half(A,  m0, 32, &lds[0][0][1][0], t);
    stage_half(Bt, n0, 32, &lds[0][1][1][0], t);
    stage_half(A,  m0, 64, &lds[1][0][0][0], t);
    stage_half(Bt, n0, 64, &lds[1][1][0][0], t);
    VM8(); BARX();
    a0 = frag(&lds[0][0][0][0], ra,      ko); a1 = frag(&lds[0][0][0][0], ra + 16, ko);
    a2 = frag(&lds[0][0][0][0], ra + 32, ko); a3 = frag(&lds[0][0][0][0], ra + 48, ko);
    b0 = frag(&lds[0][1][0][0], rb,      ko); b1 = frag(&lds[0][1][0][0], rb + 16, ko);
    b2 = frag(&lds[0][1][0][0], rb + 32, ko); b3 = frag(&lds[0][1][0][0], rb + 48, ko);
  }
  #pragma unroll 1
  for (; tau < tend; tau += 32) {
    long m0 = (long)(tau / NT) * 256, n0 = (long)(tau % NT) * 256;
    int tn = (tau + 32 < tend) ? tau + 32 : tau;
    long m0n = (long)(tn / NT) * 256, n0n = (long)(tn % NT) * 256;
    #pragma unroll
    for (int i = 0; i < 8; ++i)
      #pragma unroll
      for (int j2 = 0; j2 < 4; ++j2) acc[i][j2] = (f32x4){0.f, 0.f, 0.f, 0.f};
    #pragma unroll 1
    for (int j = 0; j < 10; j += 2) {
      KTILE_P(0, m0, n0, j * 64 + 96,  m0, n0, j * 64 + 128);
      KTILE_P(1, m0, n0, j * 64 + 160, m0, n0, j * 64 + 192);
    }
    KTILE_P(0, m0,  n0,  736, m0n, n0n, 0);   // J=10: ks1(11) + next ks0(K0)
    KTILE_P(1, m0n, n0n, 32,  m0n, n0n, 64);  // J=11: next ks1(K0) + next ks0(K1)
    // epilogue (register-only source; overlaps in-flight next-tile stages)
    int r0 = (lane >> 4) * 4;
    #pragma unroll
    for (int mf = 0; mf < 8; ++mf) {
      #pragma unroll
      for (int nf = 0; nf < 4; ++nf) {
        long row = m0 + wm * 128 + mf * 16 + r0;
        int col = (int)n0 + wn * 64 + nf * 16 + fl;
        if (OUTMODE == 0) {
          unsigned short* C = (unsigned short*)Cp;
          bool doexp = (n0 < 2 * DIM);
          #pragma unroll
          for (int r = 0; r < 4; ++r) {
            float v = acc[mf][nf][r];
            C[(size_t)(row + r) * Nld + col] = f2bf(doexp ? __expf(v) : v);
          }
        } else {
          float* C = (float*)Cp;
          float bb = bias[col];
          #pragma unroll
          for (int r = 0; r < 4; ++r)
            C[(size_t)(row + r) * Nld + col] = acc[mf][nf][r] + bb;
        }
      }
    }
  }
}

// ---------------- ctx partials: chunk ch of 7, rows [ch*448,(ch+1)*448) ----------------
__global__ void ctx_part(const unsigned short* __restrict__ qkv, float* __restrict__ part,
                         float* __restrict__ dpart) {
  int blk = blockIdx.x;              // 384*7
  int bh = blk / 7, ch = blk - bh * 7;
  int b = bh / NH, h = bh % NH;
  __shared__ unsigned short Et[64 * 40];
  __shared__ unsigned short Vt[64 * 40];
  __shared__ float denom[64];
  int t = threadIdx.x, lane = t & 63, w = t >> 6;
  if (t < 64) denom[t] = 0.0f;
  int nl = t >> 3, e0 = (t & 7) * 8;
  int ko = (lane >> 4) * 8, fl = lane & 15;
  size_t base = (size_t)b * SEQ * QKVC + (size_t)h * HD;
  float dp[8] = {};
  f32x4 acc[4] = {};
  int c0b = ch * 448;
  for (int c0 = c0b; c0 < c0b + 448; c0 += 32) {
    __syncthreads();
    size_t rb = base + (size_t)(c0 + nl) * QKVC;
    uint4 kvec = *(const uint4*)(qkv + rb + DIM + e0);
    uint4 vvec = *(const uint4*)(qkv + rb + 2 * DIM + e0);
    const unsigned short* kp = (const unsigned short*)&kvec;
    const unsigned short* vp = (const unsigned short*)&vvec;
    #pragma unroll
    for (int j = 0; j < 8; ++j) {
      dp[j] += bf2f(kp[j]);
      Et[(e0 + j) * 40 + nl] = kp[j];
      Vt[(e0 + j) * 40 + nl] = vp[j];
    }
    __syncthreads();
    bf16x8 af = *(const bf16x8*)(Et + (w * 16 + fl) * 40 + ko);
    #pragma unroll
    for (int nf = 0; nf < 4; ++nf) {
      bf16x8 bv = *(const bf16x8*)(Vt + (nf * 16 + fl) * 40 + ko);
      acc[nf] = __builtin_amdgcn_mfma_f32_16x16x32_bf16(af, bv, acc[nf], 0, 0, 0);
    }
  }
  #pragma unroll
  for (int j = 0; j < 8; ++j) atomicAdd(&denom[e0 + j], dp[j]);
  __syncthreads();
  int r0 = (lane >> 4) * 4;
  float* pp = part + (size_t)blk * 4096;
  #pragma unroll
  for (int nf = 0; nf < 4; ++nf)
    #pragma unroll
    for (int r = 0; r < 4; ++r) {
      int c = w * 16 + r0 + r;
      int d = nf * 16 + fl;
      pp[d * 64 + c] = acc[nf][r];
    }
  if (t < 64) dpart[blk * 64 + t] = denom[t];
}

// ---------------- ctx reduce over 7 chunks -> ctxT[bh][d*64+c] bf16 ----------------
__global__ void ctx_reduce(const float* __restrict__ part, const float* __restrict__ dpart,
                           unsigned short* __restrict__ ctxT) {
  int bh = blockIdx.x, t = threadIdx.x;
  const float* pp = part + (size_t)bh * 7 * 4096;
  const float* dd = dpart + (size_t)bh * 7 * 64;
  #pragma unroll
  for (int i = 0; i < 16; ++i) {
    int idx = i * 256 + t;
    float s = 0.f, ds = 0.f;
    #pragma unroll
    for (int c = 0; c < 7; ++c) {
      s += pp[c * 4096 + idx];
      ds += dd[c * 64 + (idx & 63)];
    }
    ctxT[(size_t)bh * 4096 + idx] = f2bf(s / ds);
  }
}

// ---------------- PV: out[n][d] = (sum_c eq[n][c] ctx[c][d]) / sum_c eq[n][c] ----------------
__global__ void pv_kernel(const unsigned short* __restrict__ qkv, const unsigned short* __restrict__ ctxT,
                          unsigned short* __restrict__ aout) {
  int bid = blockIdx.x;
  int bh = bid / 49, chunk = bid - bh * 49;
  int b = bh / NH, h = bh % NH;
  int n0 = chunk * 64;
  __shared__ unsigned short P[64 * 80];
  __shared__ unsigned short CT[64 * 80];
  __shared__ float srow[64];
  int t = threadIdx.x, lane = t & 63, w = t >> 6;
  int ko = (lane >> 4) * 8, fl = lane & 15;
  if (t < 64) srow[t] = 0.0f;
  {
    int d = t >> 2, cq = (t & 3) * 16;
    const uint4* src = (const uint4*)(ctxT + (size_t)bh * 4096 + d * 64 + cq);
    *(uint4*)(CT + d * 80 + cq) = src[0];
    *(uint4*)(CT + d * 80 + cq + 8) = src[1];
  }
  __syncthreads();
  {
    int nl = t >> 2, cq = (t & 3) * 16;
    size_t rb = (size_t)(b * SEQ + n0 + nl) * QKVC + h * HD + cq;
    uint4 q0 = *(const uint4*)(qkv + rb);
    uint4 q1 = *(const uint4*)(qkv + rb + 8);
    *(uint4*)(P + nl * 80 + cq) = q0;
    *(uint4*)(P + nl * 80 + cq + 8) = q1;
    const unsigned short* qp0 = (const unsigned short*)&q0;
    const unsigned short* qp1 = (const unsigned short*)&q1;
    float s = 0.0f;
    #pragma unroll
    for (int j = 0; j < 8; ++j) s += bf2f(qp0[j]) + bf2f(qp1[j]);
    atomicAdd(&srow[nl], s);
  }
  __syncthreads();
  f32x4 acc[4] = {};
  #pragma unroll
  for (int kk = 0; kk < 2; ++kk) {
    bf16x8 af = *(const bf16x8*)(P + (w * 16 + fl) * 80 + kk * 32 + ko);
    #pragma unroll
    for (int nf = 0; nf < 4; ++nf) {
      bf16x8 bv = *(const bf16x8*)(CT + (nf * 16 + fl) * 80 + kk * 32 + ko);
      acc[nf] = __builtin_amdgcn_mfma_f32_16x16x32_bf16(af, bv, acc[nf], 0, 0, 0);
    }
  }
  int r0 = (lane >> 4) * 4;
  #pragma unroll
  for (int nf = 0; nf < 4; ++nf)
    #pragma unroll
    for (int r = 0; r < 4; ++r) {
      int nlr = w * 16 + r0 + r;
      int d = nf * 16 + fl;
      float v = acc[nf][r] / srow[nlr];
      aout[(size_t)(b * SEQ + n0 + nlr) * DIM + h * HD + d] = f2bf(v);
    }
}

extern "C" void kernel_launch(void* const* d_in, const int* in_sizes, int n_in,
                              void* d_out, int out_size, void* d_ws, size_t ws_size,
                              hipStream_t stream) {
  const float* x      = (const float*)d_in[0];
  const float* w_qkv  = (const float*)d_in[1];
  const float* w_proj = (const float*)d_in[2];
  const float* b_proj = (const float*)d_in[3];
  char* ws = (char*)d_ws;
  unsigned short* x_bf    = (unsigned short*)(ws);
  unsigned short* wt_qkv  = (unsigned short*)(ws + 154140672);
  unsigned short* wt_proj = (unsigned short*)(ws + 157679616);
  unsigned short* qkv     = (unsigned short*)(ws + 158859264);
  unsigned short* ctxT    = (unsigned short*)(ws + 154140672);  // alias wt_qkv (dead after GEMM1)
  float* part  = (float*)(ws);                 // alias x_bf region (dead after GEMM1), 44.0 MB
  float* dpart = (float*)(ws + 44040192);      // 688 KB
  unsigned short* aout = (unsigned short*)(ws);  // alias x_bf/part (partials dead after reduce)

  conv_kernel<<<2048, 256, 0, stream>>>(x, x_bf, (long)M_TOT * DIM);
  transp_kernel<<<dim3(QKVC / 32, DIM / 32), dim3(32, 8), 0, stream>>>(w_qkv, wt_qkv, DIM, QKVC);
  transp_kernel<<<dim3(DIM / 32, DIM / 32), dim3(32, 8), 0, stream>>>(w_proj, wt_proj, DIM, DIM);
  gemm256p<0, 9><<<256, 512, 0, stream>>>(x_bf, wt_qkv, qkv, nullptr, QKVC, 441);
  ctx_part<<<BATCH * NH * 7, 256, 0, stream>>>(qkv, part, dpart);
  ctx_reduce<<<BATCH * NH, 256, 0, stream>>>(part, dpart, ctxT);
  pv_kernel<<<BATCH * NH * (SEQ / 64), 256, 0, stream>>>(qkv, ctxT, aout);
  gemm256p<1, 3><<<256, 512, 0, stream>>>(aout, wt_proj, (float*)d_out, b_proj, DIM, 147);
}

// Round 5
// 801.372 us; speedup vs baseline: 1.1340x; 1.1340x over previous
//
#include <hip/hip_runtime.h>
#include <hip/hip_bf16.h>

typedef __attribute__((ext_vector_type(8))) short bf16x8;
typedef __attribute__((ext_vector_type(4))) float f32x4;

constexpr int BATCH = 32, SEQ = 3136, DIM = 768, NH = 12, HD = 64;
constexpr int M_TOT = BATCH * SEQ;   // 100352
constexpr int QKVC  = 3 * DIM;       // 2304
constexpr int GK    = 768;           // K for both GEMMs

__device__ __forceinline__ float bf2f(unsigned short u) {
  union { unsigned int i; float f; } x; x.i = ((unsigned int)u) << 16; return x.f;
}
__device__ __forceinline__ unsigned short f2bf(float f) {
  union { float f; unsigned int i; } x; x.f = f;
  unsigned int r = x.i + 0x7FFFu + ((x.i >> 16) & 1u);
  return (unsigned short)(r >> 16);
}
__device__ __forceinline__ unsigned int pack2(float lo, float hi) {
  return (unsigned int)f2bf(lo) | ((unsigned int)f2bf(hi) << 16);
}
__device__ __forceinline__ void gload_lds16(const unsigned short* g, unsigned short* l) {
  __builtin_amdgcn_global_load_lds(
      (const __attribute__((address_space(1))) void*)g,
      (__attribute__((address_space(3))) void*)l, 16, 0, 0);
}

#define BARX()  asm volatile("s_barrier" ::: "memory")
#define LGKM0() asm volatile("s_waitcnt lgkmcnt(0)" ::: "memory")
#define VM8()   asm volatile("s_waitcnt vmcnt(8)" ::: "memory")
#define VM6()   asm volatile("s_waitcnt vmcnt(6)" ::: "memory")
#define SB0()   __builtin_amdgcn_sched_barrier(0)

// ---------------- fp32 -> bf16 elementwise ----------------
__global__ void conv_kernel(const float* __restrict__ in, unsigned short* __restrict__ out, long n) {
  long i = ((long)blockIdx.x * blockDim.x + threadIdx.x) * 8;
  long stride = (long)gridDim.x * blockDim.x * 8;
  for (; i < n; i += stride) {
    float4 a = *(const float4*)(in + i);
    float4 b = *(const float4*)(in + i + 4);
    uint4 o;
    o.x = pack2(a.x, a.y); o.y = pack2(a.z, a.w);
    o.z = pack2(b.x, b.y); o.w = pack2(b.z, b.w);
    *(uint4*)(out + i) = o;
  }
}

// ---------------- transpose+convert: w[K][N] fp32 -> wt[N][K] bf16 ----------------
__global__ void transp_kernel(const float* __restrict__ w, unsigned short* __restrict__ wt, int K, int N) {
  __shared__ float tile[32][33];
  int n0 = blockIdx.x * 32, k0 = blockIdx.y * 32;
  int tx = threadIdx.x, ty = threadIdx.y;
  #pragma unroll
  for (int i = 0; i < 32; i += 8)
    tile[ty + i][tx] = w[(size_t)(k0 + ty + i) * N + n0 + tx];
  __syncthreads();
  #pragma unroll
  for (int i = 0; i < 32; i += 8)
    wt[(size_t)(n0 + ty + i) * K + k0 + tx] = f2bf(tile[tx][ty + i]);
}

// ---------------- persistent 256x256x64 GEMM, reads-after-MFMA reg pipeline ----------------
__device__ __forceinline__ void stage_half(const unsigned short* __restrict__ G, long row0, int col0,
                                           unsigned short* ldsHalf, int t) {
  int r = t >> 2;
  int gslot = (t & 3) ^ ((t >> 3) & 3);
  char* dst = (char*)ldsHalf + ((t >> 6) << 10);  // wave-uniform base; HW adds lane*16
  gload_lds16(G + (row0 + r) * (long)GK + col0 + gslot * 8, (unsigned short*)dst);
  gload_lds16(G + (row0 + 128 + r) * (long)GK + col0 + gslot * 8, (unsigned short*)(dst + 8192));
}
__device__ __forceinline__ bf16x8 frag(const unsigned short* half, int r, int ko) {
  return *(const bf16x8*)((const char*)half + r * 64 + ((((ko >> 3) ^ ((r >> 1) & 3))) << 4));
}

#define MM16G(Q,A0,A1,A2,A3,B0,B1,B2,B3) do { \
  acc[(Q)+0][0]=__builtin_amdgcn_mfma_f32_16x16x32_bf16(A0,B0,acc[(Q)+0][0],0,0,0); \
  acc[(Q)+0][1]=__builtin_amdgcn_mfma_f32_16x16x32_bf16(A0,B1,acc[(Q)+0][1],0,0,0); \
  acc[(Q)+0][2]=__builtin_amdgcn_mfma_f32_16x16x32_bf16(A0,B2,acc[(Q)+0][2],0,0,0); \
  acc[(Q)+0][3]=__builtin_amdgcn_mfma_f32_16x16x32_bf16(A0,B3,acc[(Q)+0][3],0,0,0); \
  acc[(Q)+1][0]=__builtin_amdgcn_mfma_f32_16x16x32_bf16(A1,B0,acc[(Q)+1][0],0,0,0); \
  acc[(Q)+1][1]=__builtin_amdgcn_mfma_f32_16x16x32_bf16(A1,B1,acc[(Q)+1][1],0,0,0); \
  acc[(Q)+1][2]=__builtin_amdgcn_mfma_f32_16x16x32_bf16(A1,B2,acc[(Q)+1][2],0,0,0); \
  acc[(Q)+1][3]=__builtin_amdgcn_mfma_f32_16x16x32_bf16(A1,B3,acc[(Q)+1][3],0,0,0); \
  acc[(Q)+2][0]=__builtin_amdgcn_mfma_f32_16x16x32_bf16(A2,B0,acc[(Q)+2][0],0,0,0); \
  acc[(Q)+2][1]=__builtin_amdgcn_mfma_f32_16x16x32_bf16(A2,B1,acc[(Q)+2][1],0,0,0); \
  acc[(Q)+2][2]=__builtin_amdgcn_mfma_f32_16x16x32_bf16(A2,B2,acc[(Q)+2][2],0,0,0); \
  acc[(Q)+2][3]=__builtin_amdgcn_mfma_f32_16x16x32_bf16(A2,B3,acc[(Q)+2][3],0,0,0); \
  acc[(Q)+3][0]=__builtin_amdgcn_mfma_f32_16x16x32_bf16(A3,B0,acc[(Q)+3][0],0,0,0); \
  acc[(Q)+3][1]=__builtin_amdgcn_mfma_f32_16x16x32_bf16(A3,B1,acc[(Q)+3][1],0,0,0); \
  acc[(Q)+3][2]=__builtin_amdgcn_mfma_f32_16x16x32_bf16(A3,B2,acc[(Q)+3][2],0,0,0); \
  acc[(Q)+3][3]=__builtin_amdgcn_mfma_f32_16x16x32_bf16(A3,B3,acc[(Q)+3][3],0,0,0); \
} while (0)

// K-tile, reads-after-MFMA order. Each phase:
//   LGKM0 (prev-phase reads now drained); MFMA cluster; next-phase frag ds_reads;
//   stage; [VM6 at P1/P3]; BARX.
// VM6 ledger: at VM6(P1,J) the 6 newer loads are S3,S4(J-1)+S1(J) -> confirms
// S1,S2(J-1)=ks1(J), read at end-P2(J) (one barrier later, all-waves-safe).
// VM6(P3,J) confirms S3,S4(J-1)=ks0(J+1), read at end-P4(J). Holds for prologue
// (halves 3,4 / 5,6) and across tile seams. WAR: every region's last ds_read
// drains >=2 barriers before its overwriting stage issues (checked per region).
#define KTILE_W(BUF, MA2, NB2, C2, MA3, NB3, C3) { \
  const unsigned short* Ah0 = &lds[BUF][0][0][0]; \
  const unsigned short* Bh1 = &lds[BUF][1][1][0]; \
  const unsigned short* Ah1 = &lds[BUF][0][1][0]; \
  const unsigned short* Ah0n = &lds[(BUF) ^ 1][0][0][0]; \
  const unsigned short* Bh0n = &lds[(BUF) ^ 1][1][0][0]; \
  /* P1: MFMA ks0/mq0 (a0-3 x b0-3); reads a4-7 <- ks0 mq1; stage S1; VM6 */ \
  LGKM0(); SB0(); \
  __builtin_amdgcn_s_setprio(1); MM16G(0, a0, a1, a2, a3, b0, b1, b2, b3); \
  __builtin_amdgcn_s_setprio(0); SB0(); \
  a4 = frag(Ah0, ra + 64, ko); a5 = frag(Ah0, ra + 80, ko); \
  a6 = frag(Ah0, ra + 96, ko); a7 = frag(Ah0, ra + 112, ko); \
  stage_half(A, MA2, C2, &lds[(BUF) ^ 1][0][1][0], t); \
  VM6(); BARX(); \
  /* P2: MFMA ks0/mq1 (a4-7 x b0-3); reads a0-3 <- ks1 mq0, b4-7 <- ks1; stage S2 */ \
  LGKM0(); SB0(); \
  __builtin_amdgcn_s_setprio(1); MM16G(4, a4, a5, a6, a7, b0, b1, b2, b3); \
  __builtin_amdgcn_s_setprio(0); SB0(); \
  a0 = frag(Ah1, ra,      ko); a1 = frag(Ah1, ra + 16, ko); \
  a2 = frag(Ah1, ra + 32, ko); a3 = frag(Ah1, ra + 48, ko); \
  b4 = frag(Bh1, rb,      ko); b5 = frag(Bh1, rb + 16, ko); \
  b6 = frag(Bh1, rb + 32, ko); b7 = frag(Bh1, rb + 48, ko); \
  stage_half(Bt, NB2, C2, &lds[(BUF) ^ 1][1][1][0], t); \
  BARX(); \
  /* P3: MFMA ks1/mq0 (a0-3 x b4-7); reads a4-7 <- ks1 mq1; stage S3; VM6 */ \
  LGKM0(); SB0(); \
  __builtin_amdgcn_s_setprio(1); MM16G(0, a0, a1, a2, a3, b4, b5, b6, b7); \
  __builtin_amdgcn_s_setprio(0); SB0(); \
  a4 = frag(Ah1, ra + 64, ko); a5 = frag(Ah1, ra + 80, ko); \
  a6 = frag(Ah1, ra + 96, ko); a7 = frag(Ah1, ra + 112, ko); \
  stage_half(A, MA3, C3, &lds[BUF][0][0][0], t); \
  VM6(); BARX(); \
  /* P4: MFMA ks1/mq1 (a4-7 x b4-7); reads a0-3,b0-3 <- next ks0; stage S4 */ \
  LGKM0(); SB0(); \
  __builtin_amdgcn_s_setprio(1); MM16G(4, a4, a5, a6, a7, b4, b5, b6, b7); \
  __builtin_amdgcn_s_setprio(0); SB0(); \
  a0 = frag(Ah0n, ra,      ko); a1 = frag(Ah0n, ra + 16, ko); \
  a2 = frag(Ah0n, ra + 32, ko); a3 = frag(Ah0n, ra + 48, ko); \
  b0 = frag(Bh0n, rb,      ko); b1 = frag(Bh0n, rb + 16, ko); \
  b2 = frag(Bh0n, rb + 32, ko); b3 = frag(Bh0n, rb + 48, ko); \
  stage_half(Bt, NB3, C3, &lds[BUF][1][0][0], t); \
  BARX(); \
}

template<int OUTMODE, int NT>
__global__ __launch_bounds__(512, 2) void gemm256p(const unsigned short* __restrict__ A,
                                                   const unsigned short* __restrict__ Bt,
                                                   void* __restrict__ Cp,
                                                   const float* __restrict__ bias,
                                                   int Nld, int TPX) {
  __shared__ unsigned short lds[2][2][2][8192];  // [buf][A/B][ks][256*32], 128 KiB
  int t = threadIdx.x, lane = t & 63, wid = t >> 6;
  int wm = wid >> 2, wn = wid & 3;
  int bid = (int)blockIdx.x;
  int xcd = bid & 7, slot = bid >> 3;
  int tau = xcd * TPX + slot;
  int tend = (xcd + 1) * TPX;
  int fl = lane & 15, ko = (lane >> 4) * 8;
  int ra = wm * 128 + fl, rb = wn * 64 + fl;
  f32x4 acc[8][4];
  bf16x8 a0, a1, a2, a3, a4, a5, a6, a7, b0, b1, b2, b3, b4, b5, b6, b7;
  // prologue: stage tile0 buf0(ks0,ks1) + buf1(ks0); VM8 confirms ks0(0); prime frags
  {
    long m0 = (long)(tau / NT) * 256, n0 = (long)(tau % NT) * 256;
    stage_half(A,  m0, 0,  &lds[0][0][0][0], t);
    stage_half(Bt, n0, 0,  &lds[0][1][0][0], t);
    stage_half(A,  m0, 32, &lds[0][0][1][0], t);
    stage_half(Bt, n0, 32, &lds[0][1][1][0], t);
    stage_half(A,  m0, 64, &lds[1][0][0][0], t);
    stage_half(Bt, n0, 64, &lds[1][1][0][0], t);
    VM8(); BARX();
    a0 = frag(&lds[0][0][0][0], ra,      ko); a1 = frag(&lds[0][0][0][0], ra + 16, ko);
    a2 = frag(&lds[0][0][0][0], ra + 32, ko); a3 = frag(&lds[0][0][0][0], ra + 48, ko);
    b0 = frag(&lds[0][1][0][0], rb,      ko); b1 = frag(&lds[0][1][0][0], rb + 16, ko);
    b2 = frag(&lds[0][1][0][0], rb + 32, ko); b3 = frag(&lds[0][1][0][0], rb + 48, ko);
  }
  #pragma unroll 1
  for (; tau < tend; tau += 32) {
    long m0 = (long)(tau / NT) * 256, n0 = (long)(tau % NT) * 256;
    int tn = (tau + 32 < tend) ? tau + 32 : tau;
    long m0n = (long)(tn / NT) * 256, n0n = (long)(tn % NT) * 256;
    #pragma unroll
    for (int i = 0; i < 8; ++i)
      #pragma unroll
      for (int j2 = 0; j2 < 4; ++j2) acc[i][j2] = (f32x4){0.f, 0.f, 0.f, 0.f};
    #pragma unroll 1
    for (int j = 0; j < 10; j += 2) {
      KTILE_W(0, m0, n0, j * 64 + 96,  m0, n0, j * 64 + 128);
      KTILE_W(1, m0, n0, j * 64 + 160, m0, n0, j * 64 + 192);
    }
    KTILE_W(0, m0,  n0,  736, m0n, n0n, 0);   // J=10: ks1(11) + next ks0(K0)
    KTILE_W(1, m0n, n0n, 32,  m0n, n0n, 64);  // J=11: next ks1(K0) + buf1 ks0(K1)
    // epilogue (register-only source; overlaps in-flight next-tile stages)
    int r0 = (lane >> 4) * 4;
    #pragma unroll
    for (int mf = 0; mf < 8; ++mf) {
      #pragma unroll
      for (int nf = 0; nf < 4; ++nf) {
        long row = m0 + wm * 128 + mf * 16 + r0;
        int col = (int)n0 + wn * 64 + nf * 16 + fl;
        if (OUTMODE == 0) {
          unsigned short* C = (unsigned short*)Cp;
          bool doexp = (n0 < 2 * DIM);
          #pragma unroll
          for (int r = 0; r < 4; ++r) {
            float v = acc[mf][nf][r];
            C[(size_t)(row + r) * Nld + col] = f2bf(doexp ? __expf(v) : v);
          }
        } else {
          float* C = (float*)Cp;
          float bb = bias[col];
          #pragma unroll
          for (int r = 0; r < 4; ++r)
            C[(size_t)(row + r) * Nld + col] = acc[mf][nf][r] + bb;
        }
      }
    }
  }
}

// ---------------- ctx partials: chunk ch of 7, rows [ch*448,(ch+1)*448) ----------------
__global__ void ctx_part(const unsigned short* __restrict__ qkv, float* __restrict__ part,
                         float* __restrict__ dpart) {
  int blk = blockIdx.x;              // 384*7
  int bh = blk / 7, ch = blk - bh * 7;
  int b = bh / NH, h = bh % NH;
  __shared__ unsigned short Et[64 * 40];
  __shared__ unsigned short Vt[64 * 40];
  __shared__ float denom[64];
  int t = threadIdx.x, lane = t & 63, w = t >> 6;
  if (t < 64) denom[t] = 0.0f;
  int nl = t >> 3, e0 = (t & 7) * 8;
  int ko = (lane >> 4) * 8, fl = lane & 15;
  size_t base = (size_t)b * SEQ * QKVC + (size_t)h * HD;
  float dp[8] = {};
  f32x4 acc[4] = {};
  int c0b = ch * 448;
  for (int c0 = c0b; c0 < c0b + 448; c0 += 32) {
    __syncthreads();
    size_t rb = base + (size_t)(c0 + nl) * QKVC;
    uint4 kvec = *(const uint4*)(qkv + rb + DIM + e0);
    uint4 vvec = *(const uint4*)(qkv + rb + 2 * DIM + e0);
    const unsigned short* kp = (const unsigned short*)&kvec;
    const unsigned short* vp = (const unsigned short*)&vvec;
    #pragma unroll
    for (int j = 0; j < 8; ++j) {
      dp[j] += bf2f(kp[j]);
      Et[(e0 + j) * 40 + nl] = kp[j];
      Vt[(e0 + j) * 40 + nl] = vp[j];
    }
    __syncthreads();
    bf16x8 af = *(const bf16x8*)(Et + (w * 16 + fl) * 40 + ko);
    #pragma unroll
    for (int nf = 0; nf < 4; ++nf) {
      bf16x8 bv = *(const bf16x8*)(Vt + (nf * 16 + fl) * 40 + ko);
      acc[nf] = __builtin_amdgcn_mfma_f32_16x16x32_bf16(af, bv, acc[nf], 0, 0, 0);
    }
  }
  #pragma unroll
  for (int j = 0; j < 8; ++j) atomicAdd(&denom[e0 + j], dp[j]);
  __syncthreads();
  int r0 = (lane >> 4) * 4;
  float* pp = part + (size_t)blk * 4096;
  #pragma unroll
  for (int nf = 0; nf < 4; ++nf)
    #pragma unroll
    for (int r = 0; r < 4; ++r) {
      int c = w * 16 + r0 + r;
      int d = nf * 16 + fl;
      pp[d * 64 + c] = acc[nf][r];
    }
  if (t < 64) dpart[blk * 64 + t] = denom[t];
}

// ---------------- ctx reduce over 7 chunks -> ctxT[bh][d*64+c] bf16 ----------------
__global__ void ctx_reduce(const float* __restrict__ part, const float* __restrict__ dpart,
                           unsigned short* __restrict__ ctxT) {
  int bh = blockIdx.x, t = threadIdx.x;
  const float* pp = part + (size_t)bh * 7 * 4096;
  const float* dd = dpart + (size_t)bh * 7 * 64;
  #pragma unroll
  for (int i = 0; i < 16; ++i) {
    int idx = i * 256 + t;
    float s = 0.f, ds = 0.f;
    #pragma unroll
    for (int c = 0; c < 7; ++c) {
      s += pp[c * 4096 + idx];
      ds += dd[c * 64 + (idx & 63)];
    }
    ctxT[(size_t)bh * 4096 + idx] = f2bf(s / ds);
  }
}

// ---------------- PV: out[n][d] = (sum_c eq[n][c] ctx[c][d]) / sum_c eq[n][c] ----------------
__global__ void pv_kernel(const unsigned short* __restrict__ qkv, const unsigned short* __restrict__ ctxT,
                          unsigned short* __restrict__ aout) {
  int bid = blockIdx.x;
  int bh = bid / 49, chunk = bid - bh * 49;
  int b = bh / NH, h = bh % NH;
  int n0 = chunk * 64;
  __shared__ unsigned short P[64 * 80];
  __shared__ unsigned short CT[64 * 80];
  __shared__ float srow[64];
  int t = threadIdx.x, lane = t & 63, w = t >> 6;
  int ko = (lane >> 4) * 8, fl = lane & 15;
  if (t < 64) srow[t] = 0.0f;
  {
    int d = t >> 2, cq = (t & 3) * 16;
    const uint4* src = (const uint4*)(ctxT + (size_t)bh * 4096 + d * 64 + cq);
    *(uint4*)(CT + d * 80 + cq) = src[0];
    *(uint4*)(CT + d * 80 + cq + 8) = src[1];
  }
  __syncthreads();
  {
    int nl = t >> 2, cq = (t & 3) * 16;
    size_t rb = (size_t)(b * SEQ + n0 + nl) * QKVC + h * HD + cq;
    uint4 q0 = *(const uint4*)(qkv + rb);
    uint4 q1 = *(const uint4*)(qkv + rb + 8);
    *(uint4*)(P + nl * 80 + cq) = q0;
    *(uint4*)(P + nl * 80 + cq + 8) = q1;
    const unsigned short* qp0 = (const unsigned short*)&q0;
    const unsigned short* qp1 = (const unsigned short*)&q1;
    float s = 0.0f;
    #pragma unroll
    for (int j = 0; j < 8; ++j) s += bf2f(qp0[j]) + bf2f(qp1[j]);
    atomicAdd(&srow[nl], s);
  }
  __syncthreads();
  f32x4 acc[4] = {};
  #pragma unroll
  for (int kk = 0; kk < 2; ++kk) {
    bf16x8 af = *(const bf16x8*)(P + (w * 16 + fl) * 80 + kk * 32 + ko);
    #pragma unroll
    for (int nf = 0; nf < 4; ++nf) {
      bf16x8 bv = *(const bf16x8*)(CT + (nf * 16 + fl) * 80 + kk * 32 + ko);
      acc[nf] = __builtin_amdgcn_mfma_f32_16x16x32_bf16(af, bv, acc[nf], 0, 0, 0);
    }
  }
  int r0 = (lane >> 4) * 4;
  #pragma unroll
  for (int nf = 0; nf < 4; ++nf)
    #pragma unroll
    for (int r = 0; r < 4; ++r) {
      int nlr = w * 16 + r0 + r;
      int d = nf * 16 + fl;
      float v = acc[nf][r] / srow[nlr];
      aout[(size_t)(b * SEQ + n0 + nlr) * DIM + h * HD + d] = f2bf(v);
    }
}

extern "C" void kernel_launch(void* const* d_in, const int* in_sizes, int n_in,
                              void* d_out, int out_size, void* d_ws, size_t ws_size,
                              hipStream_t stream) {
  const float* x      = (const float*)d_in[0];
  const float* w_qkv  = (const float*)d_in[1];
  const float* w_proj = (const float*)d_in[2];
  const float* b_proj = (const float*)d_in[3];
  char* ws = (char*)d_ws;
  unsigned short* x_bf    = (unsigned short*)(ws);
  unsigned short* wt_qkv  = (unsigned short*)(ws + 154140672);
  unsigned short* wt_proj = (unsigned short*)(ws + 157679616);
  unsigned short* qkv     = (unsigned short*)(ws + 158859264);
  unsigned short* ctxT    = (unsigned short*)(ws + 154140672);  // alias wt_qkv (dead after GEMM1)
  float* part  = (float*)(ws);                 // alias x_bf region (dead after GEMM1), 44.0 MB
  float* dpart = (float*)(ws + 44040192);      // 688 KB
  unsigned short* aout = (unsigned short*)(ws);  // alias x_bf/part (partials dead after reduce)

  conv_kernel<<<2048, 256, 0, stream>>>(x, x_bf, (long)M_TOT * DIM);
  transp_kernel<<<dim3(QKVC / 32, DIM / 32), dim3(32, 8), 0, stream>>>(w_qkv, wt_qkv, DIM, QKVC);
  transp_kernel<<<dim3(DIM / 32, DIM / 32), dim3(32, 8), 0, stream>>>(w_proj, wt_proj, DIM, DIM);
  gemm256p<0, 9><<<256, 512, 0, stream>>>(x_bf, wt_qkv, qkv, nullptr, QKVC, 441);
  ctx_part<<<BATCH * NH * 7, 256, 0, stream>>>(qkv, part, dpart);
  ctx_reduce<<<BATCH * NH, 256, 0, stream>>>(part, dpart, ctxT);
  pv_kernel<<<BATCH * NH * (SEQ / 64), 256, 0, stream>>>(qkv, ctxT, aout);
  gemm256p<1, 3><<<256, 512, 0, stream>>>(aout, wt_proj, (float*)d_out, b_proj, DIM, 147);
}